// Round 1
// baseline (51.023 us; speedup 1.0000x reference)
//
#include <hip/hip_runtime.h>

// DS fusion: B=4096 rows, each a sequential fold of D=128 mass vectors of C=101.
// One wave (64 lanes) per row; lane l owns channels l and l+64.
// Normalization deferred (step is bilinear -> scale-invariant), applied every
// 8 steps + at the end. Depth-3 register prefetch to cover HBM latency.

constexpr int kB = 4096;
constexpr int kD = 128;
constexpr int kC = 101;

__global__ __launch_bounds__(256, 4) void ds_fuse_kernel(const float* __restrict__ in,
                                                         float* __restrict__ out) {
    const int wid  = (int)((blockIdx.x * (unsigned)blockDim.x + threadIdx.x) >> 6);
    const int lane = threadIdx.x & 63;
    if (wid >= kB) return;

    const float* __restrict__ row = in + (size_t)wid * (kD * kC);
    const bool hi = (lane + 64) < kC;          // lanes 0..36 own a second channel
    const int l0 = lane, l1 = lane + 64;

    // m = inputs[:,0,:]
    float m0 = row[l0];                         // l0 < 101 always (l0 <= 63)
    float m1 = hi ? row[l1] : 0.0f;             // exact 0 for dead lanes
    float om = __shfl(m1, 36);                  // omega = m[100], broadcast

    // depth-3 software prefetch pipeline (registers only)
    float a0 = row[1 * kC + l0], a1 = hi ? row[1 * kC + l1] : 0.0f;
    float b0 = row[2 * kC + l0], b1 = hi ? row[2 * kC + l1] : 0.0f;
    float c0 = row[3 * kC + l0], c1 = hi ? row[3 * kC + l1] : 0.0f;

    for (int d = 1; d < kD; ++d) {
        float p0 = 0.0f, p1 = 0.0f;
        if (d + 3 < kD) {                       // uniform branch
            const float* __restrict__ r = row + (d + 3) * kC;
            p0 = r[l0];
            p1 = hi ? r[l1] : 0.0f;
        }

        const float w2 = __shfl(a1, 36);        // omega2 = a[100] (load path, pipelined)
        // c[j] = m[j]*a[j] + m[j]*w2 + om*a[j]  (generic formula, incl. channel 100)
        const float n0 = fmaf(m0, a0 + w2, om * a0);
        const float n1 = fmaf(m1, a1 + w2, om * a1);
        // om mirrors lane36's n1 bit-exactly: there a1==w2 and m1==om.
        om = fmaf(om, w2 + w2, om * w2);
        m0 = n0; m1 = n1;

        // periodic renormalization (scale-invariance makes this exact math-wise;
        // bounds f32 range). Also normalizes at the final step (127&7 == 7... so
        // include explicit d==kD-1 term; 127&7==7 means we rely on the ||).
        if ((d & 7) == 0 || d == kD - 1) {
            float t = m0 + m1;
            #pragma unroll
            for (int off = 32; off >= 1; off >>= 1) t += __shfl_xor(t, off);
            const float inv = 1.0f / t;
            m0 *= inv; m1 *= inv; om *= inv;
        }

        a0 = b0; a1 = b1;                        // rotate pipeline (static regs)
        b0 = c0; b1 = c1;
        c0 = p0; c1 = p1;
    }

    float* __restrict__ o = out + (size_t)wid * kC;
    o[l0] = m0;
    if (hi) o[l1] = m1;
}

extern "C" void kernel_launch(void* const* d_in, const int* in_sizes, int n_in,
                              void* d_out, int out_size, void* d_ws, size_t ws_size,
                              hipStream_t stream) {
    const float* in = (const float*)d_in[0];
    float* out = (float*)d_out;
    // 4096 rows, 1 wave each, 4 waves (256 threads) per block -> 1024 blocks
    ds_fuse_kernel<<<kB / 4, 256, 0, stream>>>(in, out);
}

// Round 3
// 36.194 us; speedup vs baseline: 1.4097x; 1.4097x over previous
//
#include <hip/hip_runtime.h>
#include <stdint.h>

// DS fusion as independent per-channel linear recurrences.
// Substitution M_j = m_j + omega turns the (unnormalized) DS step
//   c_j = m_j x_j + m_j nu + omega x_j ,  omega' = 3 omega nu
// into   M'_j = M_j (x_j + nu) + 2 omega nu   (exact algebra).
// Each thread owns one (row, channel): 1 fma + ~4 VALU per step, zero
// cross-lane traffic in the hot loop. Scale overflow handled by exact
// power-of-2 renorm every 8 steps (int exponent accumulator E).
// Epilogue: per-row Emax + sum reduction, out_j = v_j / S.

constexpr int kB   = 4096;
constexpr int kD   = 128;
constexpr int kC   = 101;
constexpr int kRow = kD * kC;   // 12928 floats per row

__global__ __launch_bounds__(256, 4) void ds_scan_kernel(const float* __restrict__ in,
                                                         float* __restrict__ out) {
    const int tid  = threadIdx.x;
    const int rloc = tid >> 7;                 // row within block (0..1)
    const int j    = tid & 127;                // channel slot (0..127)
    const int b    = blockIdx.x * 2 + rloc;
    const bool live = j < kC;
    const int  jc   = live ? j : (kC - 1);     // idle lanes mirror the nu thread

    const float* __restrict__ base = in + (size_t)b * kRow;

    // t = 0: m_init
    const float nu0 = base[kC - 1];
    float M = base[jc] + nu0;                  // M_j = m_j + omega
    float w = nu0;                             // per-thread omega copy
    int   E = 0;                               // accumulated exponent (exact)

    auto step = [&](int t) {
        const float* __restrict__ r = base + t * kC;
        const float xt = r[jc];
        const float nt = r[kC - 1];
        const float Xi = xt + nt;
        const float P  = w * nt;
        const float P2 = P + P;
        M = fmaf(M, Xi, P2);                   // M' = M*Xi + 2*omega*nu
        w = P + P2;                            // omega' = 3*omega*nu
    };
    auto renorm = [&]() {                      // exact: scale by 2^(127-e)
        const float s = M + w;
        const uint32_t eb = (__float_as_uint(s) >> 23) & 0xFFu;
        const float scale = __uint_as_float((254u - eb) << 23);
        M *= scale; w *= scale;
        E += (int)eb - 127;
    };

    int t = 1;
    #pragma unroll
    for (int s = 0; s < 7; ++s, ++t) step(t);  // t = 1..7
    for (int g = 0; g < 15; ++g) {             // 15 groups of 8: t = 8..127
        #pragma unroll
        for (int s = 0; s < 8; ++s, ++t) step(t);
        renorm();
    }

    // ---- epilogue: common scale + normalize across the row's 101 channels
    float v  = live ? (M - w) : 0.0f;          // unnormalized mass * 2^E
    int   Ee = live ? E : (int)0xC0000000;     // idle lanes excluded from max

    int em = Ee;
    #pragma unroll
    for (int off = 32; off >= 1; off >>= 1) em = max(em, __shfl_xor(em, off));

    __shared__ int   sE[4];
    __shared__ float sV[4];
    const int wave = tid >> 6;
    if ((tid & 63) == 0) sE[wave] = em;
    __syncthreads();
    const int w0   = rloc * 2;
    const int Emax = max(sE[w0], sE[w0 + 1]);

    const int d = (live ? E : 0) - Emax;       // <= 0
    const float sc = (d < -126) ? 0.0f
                   : __uint_as_float((uint32_t)(d + 127) << 23);  // 2^d exact
    v *= sc;

    float sv = v;
    #pragma unroll
    for (int off = 32; off >= 1; off >>= 1) sv += __shfl_xor(sv, off);
    if ((tid & 63) == 0) sV[wave] = sv;
    __syncthreads();
    const float S = sV[w0] + sV[w0 + 1];

    if (live) out[(size_t)b * kC + j] = v / S;
}

extern "C" void kernel_launch(void* const* d_in, const int* in_sizes, int n_in,
                              void* d_out, int out_size, void* d_ws, size_t ws_size,
                              hipStream_t stream) {
    const float* in = (const float*)d_in[0];
    float* out = (float*)d_out;
    // 2 rows per 256-thread block -> 2048 blocks (8/CU), 128 threads per row
    ds_scan_kernel<<<kB / 2, 256, 0, stream>>>(in, out);
}

// Round 4
// 35.798 us; speedup vs baseline: 1.4253x; 1.0111x over previous
//
#include <hip/hip_runtime.h>
#include <stdint.h>

// DS fusion as independent per-channel linear recurrences (see R3):
//   M'_j = M_j (x_j + nu) + 2 omega nu ,  omega' = 3 omega nu   (exact algebra,
// with M_j = m_j + omega and normalization deferred / power-of-2 renorm).
//
// This round: one WAVE per row, float2 per lane.
//  - lane l<50 owns channels (2l, 2l+1) via one 8B load (align-4 dwordx2;
//    row stride 101 floats is odd so alignment alternates with t)
//  - lane 50 loads pair (99,100): its .y is channel 100; lanes 51..63 mirror it
//  - omega2 (nu) comes from __shfl(v.y, 50): NO broadcast load ->
//    exactly 1 VMEM instruction per step per wave (512B request)
//  - epilogue reduction is wave-local: no LDS, no __syncthreads

constexpr int kB   = 4096;
constexpr int kD   = 128;
constexpr int kC   = 101;
constexpr int kRow = kD * kC;

typedef float f2 __attribute__((ext_vector_type(2)));

__device__ __forceinline__ f2 load_f2(const float* p) {
    f2 v; __builtin_memcpy(&v, p, 8); return v;   // align-4 dwordx2
}

__global__ __launch_bounds__(256, 4) void ds_scan2_kernel(const float* __restrict__ in,
                                                          float* __restrict__ out) {
    const int lane = threadIdx.x & 63;
    const int wave = threadIdx.x >> 6;
    const int b    = blockIdx.x * 4 + wave;

    const bool pair_live = lane < 50;              // owns channels 2l, 2l+1
    const int  off       = pair_live ? 2 * lane : 99;
    const float* __restrict__ base = in + (size_t)b * kRow;

    // t = 0
    f2 v = load_f2(base + off);
    const float nu0 = __shfl(v.y, 50);             // channel 100
    float M0 = v.x + nu0;                          // M_j = m_j + omega
    float M1 = v.y + nu0;
    float w  = nu0;                                // per-lane omega copy
    int   E  = 0;                                  // exact exponent accumulator

    auto step = [&](int t) {
        const f2 x = load_f2(base + t * kC + off);
        const float n  = __shfl(x.y, 50);          // nu_t
        const float P  = w * n;
        const float P2 = P + P;
        M0 = fmaf(M0, x.x + n, P2);                // M' = M*(x+nu) + 2*omega*nu
        M1 = fmaf(M1, x.y + n, P2);
        w  = P + P2;                               // omega' = 3*omega*nu
    };
    auto renorm = [&]() {                          // exact power-of-2 rescale
        const float s = M0 + M1 + w;               // all non-negative
        const uint32_t eb = (__float_as_uint(s) >> 23) & 0xFFu;
        const float scale = __uint_as_float((254u - eb) << 23);
        M0 *= scale; M1 *= scale; w *= scale;
        E += (int)eb - 127;
    };

    int t = 1;
    #pragma unroll
    for (int s = 0; s < 7; ++s, ++t) step(t);      // t = 1..7
    for (int g = 0; g < 15; ++g) {                 // t = 8..127, renorm per 8
        #pragma unroll
        for (int s = 0; s < 8; ++s, ++t) step(t);
        renorm();
    }

    // ---- epilogue (wave-local): common scale, sum, normalize, store
    int em = E;                                    // dead lanes mirror lane 50
    #pragma unroll
    for (int o = 32; o >= 1; o >>= 1) em = max(em, __shfl_xor(em, o));

    const int d = E - em;                          // <= 0
    const float sc = (d < -126) ? 0.0f
                   : __uint_as_float((uint32_t)(d + 127) << 23);   // 2^d exact

    float v0 = pair_live   ? (M0 - w) * sc : 0.0f; // lane50's M0 dups ch99: mask
    float v1 = (lane <= 50) ? (M1 - w) * sc : 0.0f;

    float sv = v0 + v1;
    #pragma unroll
    for (int o = 32; o >= 1; o >>= 1) sv += __shfl_xor(sv, o);
    const float S = sv;

    float* __restrict__ o = out + (size_t)b * kC;
    if (pair_live) {
        f2 r; r.x = v0 / S; r.y = v1 / S;
        __builtin_memcpy(o + off, &r, 8);          // align-4 dwordx2 store
    } else if (lane == 50) {
        o[100] = v1 / S;
    }
}

extern "C" void kernel_launch(void* const* d_in, const int* in_sizes, int n_in,
                              void* d_out, int out_size, void* d_ws, size_t ws_size,
                              hipStream_t stream) {
    const float* in = (const float*)d_in[0];
    float* out = (float*)d_out;
    // 1 wave per row, 4 rows per 256-thread block -> 1024 blocks
    ds_scan2_kernel<<<kB / 4, 256, 0, stream>>>(in, out);
}